// Round 1
// baseline (182.957 us; speedup 1.0000x reference)
//
#include <hip/hip_runtime.h>
#include <stdint.h>
#include <stddef.h>

typedef _Float16 half_t;
typedef __attribute__((ext_vector_type(8))) _Float16 h16x8;
typedef __attribute__((ext_vector_type(4))) _Float16 h16x4;
typedef __attribute__((ext_vector_type(4))) float f32x4;

#define MFMA16(a, b, c) __builtin_amdgcn_mfma_f32_16x16x32_f16(a, b, c, 0, 0, 0)

// ---------------------------------------------------------------------------
// Kernel 0a: convert x fp32 -> fp16
// ---------------------------------------------------------------------------
__global__ __launch_bounds__(256) void cvt_x_kernel(const float* __restrict__ x,
                                                    half_t* __restrict__ xh, int n8) {
    int i = blockIdx.x * blockDim.x + threadIdx.x;
    if (i >= n8) return;
    const float4* xv = (const float4*)x;
    float4 a = xv[i * 2 + 0];
    float4 b = xv[i * 2 + 1];
    h16x8 o;
    o[0] = (half_t)a.x; o[1] = (half_t)a.y; o[2] = (half_t)a.z; o[3] = (half_t)a.w;
    o[4] = (half_t)b.x; o[5] = (half_t)b.y; o[6] = (half_t)b.z; o[7] = (half_t)b.w;
    ((h16x8*)xh)[i] = o;
}

// ---------------------------------------------------------------------------
// Kernel 0b: transpose + convert W [k][n] fp32 -> Wt [p][n][k] fp16
// grid (32, 32, 3), block 256. 32x32 tiles via LDS.
// ---------------------------------------------------------------------------
__global__ __launch_bounds__(256) void cvt_w_kernel(const float* __restrict__ Wq,
                                                    const float* __restrict__ Wk,
                                                    const float* __restrict__ Wv,
                                                    half_t* __restrict__ Wt) {
    __shared__ float t[32][33];
    const float* W = (blockIdx.z == 0) ? Wq : ((blockIdx.z == 1) ? Wk : Wv);
    int k0 = blockIdx.y * 32, n0 = blockIdx.x * 32;
    int tid = threadIdx.x;
    int r = tid >> 3;          // 0..31
    int c4 = (tid & 7) * 4;    // 0..28
    float4 v = *(const float4*)&W[(size_t)(k0 + r) * 1024 + n0 + c4];
    t[r][c4 + 0] = v.x; t[r][c4 + 1] = v.y; t[r][c4 + 2] = v.z; t[r][c4 + 3] = v.w;
    __syncthreads();
    // write Wt[z][n0+r][k0+c4 .. +3] = t[c4+j][r]
    half_t* o = Wt + (size_t)blockIdx.z * 1024 * 1024 + (size_t)(n0 + r) * 1024 + k0 + c4;
    h16x4 h;
    h[0] = (half_t)t[c4 + 0][r];
    h[1] = (half_t)t[c4 + 1][r];
    h[2] = (half_t)t[c4 + 2][r];
    h[3] = (half_t)t[c4 + 3][r];
    *(h16x4*)o = h;
}

// ---------------------------------------------------------------------------
// Kernel 1: QKV projection GEMM.  Y = xh @ W + b, stored fp16 in head layout
// qkv[p][b*16+h][s][hd].   M=4096, N=1024, K=1024 per projection.
// grid (N/128=8, M/128=32, 3), block 256 (4 waves, 2x2), tile 128x128, BK=32.
// ---------------------------------------------------------------------------
__global__ __launch_bounds__(256) void gemm_qkv_kernel(
    const half_t* __restrict__ xh,   // [4096][1024]
    const half_t* __restrict__ Wt,   // [3][1024 n][1024 k]
    const float* __restrict__ bq, const float* __restrict__ bk,
    const float* __restrict__ bv,
    half_t* __restrict__ qkv)        // [3][32][2048][64]
{
    const int p = blockIdx.z;
    const float* bias = (p == 0) ? bq : ((p == 1) ? bk : bv);
    const half_t* Wp = Wt + (size_t)p * 1024 * 1024;
    const int n0 = blockIdx.x * 128, m0 = blockIdx.y * 128;

    __shared__ half_t Al[128][40];   // stride 40 halves = 80B (16B aligned rows)
    __shared__ half_t Bl[128][40];

    const int tid = threadIdx.x;
    const int lane = tid & 63, wid = tid >> 6;
    const int wm = wid >> 1, wn = wid & 1;
    const int g = lane >> 4, r = lane & 15;

    const int sr = tid >> 2;        // 0..63
    const int sc = (tid & 3) * 8;   // 0,8,16,24

    f32x4 acc[4][4];
#pragma unroll
    for (int a = 0; a < 4; a++)
#pragma unroll
        for (int c = 0; c < 4; c++) acc[a][c] = (f32x4){0.f, 0.f, 0.f, 0.f};

    for (int k0 = 0; k0 < 1024; k0 += 32) {
        __syncthreads();
        *(h16x8*)&Al[sr][sc]      = *(const h16x8*)&xh[(size_t)(m0 + sr) * 1024 + k0 + sc];
        *(h16x8*)&Al[sr + 64][sc] = *(const h16x8*)&xh[(size_t)(m0 + sr + 64) * 1024 + k0 + sc];
        *(h16x8*)&Bl[sr][sc]      = *(const h16x8*)&Wp[(size_t)(n0 + sr) * 1024 + k0 + sc];
        *(h16x8*)&Bl[sr + 64][sc] = *(const h16x8*)&Wp[(size_t)(n0 + sr + 64) * 1024 + k0 + sc];
        __syncthreads();

        h16x8 af[4], bf[4];
#pragma unroll
        for (int mi = 0; mi < 4; mi++)
            af[mi] = *(const h16x8*)&Al[wm * 64 + mi * 16 + r][g * 8];
#pragma unroll
        for (int ni = 0; ni < 4; ni++)
            bf[ni] = *(const h16x8*)&Bl[wn * 64 + ni * 16 + r][g * 8];
#pragma unroll
        for (int mi = 0; mi < 4; mi++)
#pragma unroll
            for (int ni = 0; ni < 4; ni++)
                acc[mi][ni] = MFMA16(af[mi], bf[ni], acc[mi][ni]);
    }

    // epilogue: bias + store fp16 in head layout
    float bn[4];
#pragma unroll
    for (int ni = 0; ni < 4; ni++) bn[ni] = bias[n0 + wn * 64 + ni * 16 + r];

    half_t* outp = qkv + (size_t)p * 4194304;  // 4096*1024
#pragma unroll
    for (int mi = 0; mi < 4; mi++) {
#pragma unroll
        for (int ni = 0; ni < 4; ni++) {
            int n = n0 + wn * 64 + ni * 16 + r;
            int h = n >> 6, hd = n & 63;
#pragma unroll
            for (int i = 0; i < 4; i++) {
                int m = m0 + wm * 64 + mi * 16 + g * 4 + i;
                int b = m >> 11, s = m & 2047;
                float v = acc[mi][ni][i] + bn[ni];
                outp[(((size_t)(b * 16 + h) * 2048 + s) << 6) + hd] = (half_t)v;
            }
        }
    }
}

// ---------------------------------------------------------------------------
// Kernel 2: flash attention.  grid (S/64=32, B*H=32), block 256 (4 waves).
// Wave w owns 16 q-rows. KVBLK=64. No softmax scaling (per reference).
// ---------------------------------------------------------------------------
__global__ __launch_bounds__(256) void attn_kernel(
    const half_t* __restrict__ Qg,  // [32][2048][64]
    const half_t* __restrict__ Kg,
    const half_t* __restrict__ Vg,
    float* __restrict__ out)        // [B][S][1024]
{
    __shared__ half_t Kl[64][72];       // K rows  (stride 144B)
    __shared__ half_t Vt[64][72];       // V transposed: Vt[d][k]
    __shared__ half_t Pl[4][16][72];    // per-wave P tile

    const int tid = threadIdx.x;
    const int lane = tid & 63, wid = tid >> 6;
    const int g = lane >> 4, r = lane & 15;
    const int bh = blockIdx.y;
    const int b = bh >> 4, h = bh & 15;
    const half_t* Qb = Qg + (size_t)bh * 131072;   // 2048*64
    const half_t* Kb = Kg + (size_t)bh * 131072;
    const half_t* Vb = Vg + (size_t)bh * 131072;
    const int q0 = blockIdx.x * 64 + wid * 16;

    // Q fragments (hoisted): rows q0+r, k-halves t=0,1
    h16x8 qf[2];
    qf[0] = *(const h16x8*)&Qb[(size_t)(q0 + r) * 64 + g * 8];
    qf[1] = *(const h16x8*)&Qb[(size_t)(q0 + r) * 64 + 32 + g * 8];

    f32x4 o[4];
#pragma unroll
    for (int d = 0; d < 4; d++) o[d] = (f32x4){0.f, 0.f, 0.f, 0.f};
    float m_run[4], l_run[4];
#pragma unroll
    for (int i = 0; i < 4; i++) { m_run[i] = -1e30f; l_run[i] = 0.f; }

    const int krow = tid >> 3, kc8 = (tid & 7) * 8;  // K staging
    const int vk = tid & 63, vd = (tid >> 6) * 8;    // V staging (transpose)

    for (int kt = 0; kt < 32; ++kt) {
        const half_t* Ks = Kb + (size_t)kt * 4096;   // 64*64
        const half_t* Vs = Vb + (size_t)kt * 4096;
        __syncthreads();
        // stage K (row-major, coalesced)
        *(h16x8*)&Kl[krow][kc8]      = *(const h16x8*)&Ks[krow * 64 + kc8];
        *(h16x8*)&Kl[krow + 32][kc8] = *(const h16x8*)&Ks[(krow + 32) * 64 + kc8];
        // stage V transposed (per-lane strided global reads, conflict-free LDS writes)
        h16x8 v0 = *(const h16x8*)&Vs[vk * 64 + vd];
        h16x8 v1 = *(const h16x8*)&Vs[vk * 64 + vd + 32];
#pragma unroll
        for (int j = 0; j < 8; j++) Vt[vd + j][vk] = v0[j];
#pragma unroll
        for (int j = 0; j < 8; j++) Vt[vd + 32 + j][vk] = v1[j];
        __syncthreads();

        // QK^T: E[16 q][64 k]
        f32x4 e[4];
#pragma unroll
        for (int kc = 0; kc < 4; kc++) {
            e[kc] = (f32x4){0.f, 0.f, 0.f, 0.f};
#pragma unroll
            for (int t = 0; t < 2; t++) {
                h16x8 kf = *(const h16x8*)&Kl[kc * 16 + r][t * 32 + g * 8];
                e[kc] = MFMA16(qf[t], kf, e[kc]);
            }
        }

        // online softmax (per q-row; row i lives in the 16 lanes of this g-group)
        float scale_[4];
#pragma unroll
        for (int i = 0; i < 4; i++) {
            float tm = fmaxf(fmaxf(e[0][i], e[1][i]), fmaxf(e[2][i], e[3][i]));
#pragma unroll
            for (int off = 1; off < 16; off <<= 1)
                tm = fmaxf(tm, __shfl_xor(tm, off));
            float nm = fmaxf(m_run[i], tm);
            float sc = __expf(m_run[i] - nm);
            m_run[i] = nm;
            float ps = 0.f;
#pragma unroll
            for (int kc = 0; kc < 4; kc++) {
                float pv = __expf(e[kc][i] - nm);
                e[kc][i] = pv;
                ps += pv;
            }
#pragma unroll
            for (int off = 1; off < 16; off <<= 1)
                ps += __shfl_xor(ps, off);
            l_run[i] = l_run[i] * sc + ps;
            scale_[i] = sc;
        }
#pragma unroll
        for (int d = 0; d < 4; d++)
#pragma unroll
            for (int i = 0; i < 4; i++) o[d][i] *= scale_[i];

        // P -> per-wave LDS (C-layout -> A-fragment layout transpose)
#pragma unroll
        for (int i = 0; i < 4; i++)
#pragma unroll
            for (int kc = 0; kc < 4; kc++)
                Pl[wid][g * 4 + i][kc * 16 + r] = (half_t)e[kc][i];
        asm volatile("s_waitcnt lgkmcnt(0)" ::: "memory");
        __builtin_amdgcn_sched_barrier(0);

        // PV: O += P @ V
#pragma unroll
        for (int ks = 0; ks < 2; ks++) {
            h16x8 pf = *(const h16x8*)&Pl[wid][r][ks * 32 + g * 8];
#pragma unroll
            for (int d = 0; d < 4; d++) {
                h16x8 vf = *(const h16x8*)&Vt[d * 16 + r][ks * 32 + g * 8];
                o[d] = MFMA16(pf, vf, o[d]);
            }
        }
    }

    // epilogue: normalize and store fp32
#pragma unroll
    for (int i = 0; i < 4; i++) {
        float inv = 1.0f / l_run[i];
        int s = q0 + g * 4 + i;
        float* op = out + (size_t)(b * 2048 + s) * 1024 + h * 64 + r;
#pragma unroll
        for (int d = 0; d < 4; d++) op[d * 16] = o[d][i] * inv;
    }
}

// ---------------------------------------------------------------------------
extern "C" void kernel_launch(void* const* d_in, const int* in_sizes, int n_in,
                              void* d_out, int out_size, void* d_ws, size_t ws_size,
                              hipStream_t stream) {
    const float* x  = (const float*)d_in[0];
    const float* Wq = (const float*)d_in[1];
    const float* bq = (const float*)d_in[2];
    const float* Wk = (const float*)d_in[3];
    const float* bk = (const float*)d_in[4];
    const float* Wv = (const float*)d_in[5];
    const float* bv = (const float*)d_in[6];
    float* out = (float*)d_out;

    // workspace layout (fp16):
    //   xh  : 4096*1024        @ 0        (8 MB)
    //   Wt  : 3*1024*1024      @ 8 MB     (6 MB)
    //   qkv : 3*4096*1024      @ 14 MB    (24 MB)
    half_t* xh  = (half_t*)d_ws;
    half_t* Wt  = (half_t*)((char*)d_ws + (size_t)8 * 1024 * 1024);
    half_t* qkv = (half_t*)((char*)d_ws + (size_t)14 * 1024 * 1024);
    half_t* Qh = qkv;
    half_t* Kh = qkv + (size_t)4194304;
    half_t* Vh = qkv + (size_t)8388608;

    cvt_x_kernel<<<2048, 256, 0, stream>>>(x, xh, 524288);
    cvt_w_kernel<<<dim3(32, 32, 3), 256, 0, stream>>>(Wq, Wk, Wv, Wt);
    gemm_qkv_kernel<<<dim3(8, 32, 3), 256, 0, stream>>>(xh, Wt, bq, bk, bv, qkv);
    attn_kernel<<<dim3(32, 32), 256, 0, stream>>>(Qh, Kh, Vh, out);
}

// Round 2
// 122.736 us; speedup vs baseline: 1.4906x; 1.4906x over previous
//
#include <hip/hip_runtime.h>
#include <stdint.h>
#include <stddef.h>

typedef _Float16 half_t;
typedef __attribute__((ext_vector_type(8))) _Float16 h16x8;
typedef __attribute__((ext_vector_type(4))) _Float16 h16x4;
typedef __attribute__((ext_vector_type(4))) float f32x4;

#define MFMA16(a, b, c) __builtin_amdgcn_mfma_f32_16x16x32_f16(a, b, c, 0, 0, 0)

// ---------------------------------------------------------------------------
// Kernel 0a: convert x fp32 -> fp16
// ---------------------------------------------------------------------------
__global__ __launch_bounds__(256) void cvt_x_kernel(const float* __restrict__ x,
                                                    half_t* __restrict__ xh, int n8) {
    int i = blockIdx.x * blockDim.x + threadIdx.x;
    if (i >= n8) return;
    const float4* xv = (const float4*)x;
    float4 a = xv[i * 2 + 0];
    float4 b = xv[i * 2 + 1];
    h16x8 o;
    o[0] = (half_t)a.x; o[1] = (half_t)a.y; o[2] = (half_t)a.z; o[3] = (half_t)a.w;
    o[4] = (half_t)b.x; o[5] = (half_t)b.y; o[6] = (half_t)b.z; o[7] = (half_t)b.w;
    ((h16x8*)xh)[i] = o;
}

// ---------------------------------------------------------------------------
// Kernel 0b: transpose + convert W [k][n] fp32 -> Wt [p][n][k] fp16
// ---------------------------------------------------------------------------
__global__ __launch_bounds__(256) void cvt_w_kernel(const float* __restrict__ Wq,
                                                    const float* __restrict__ Wk,
                                                    const float* __restrict__ Wv,
                                                    half_t* __restrict__ Wt) {
    __shared__ float t[32][33];
    const float* W = (blockIdx.z == 0) ? Wq : ((blockIdx.z == 1) ? Wk : Wv);
    int k0 = blockIdx.y * 32, n0 = blockIdx.x * 32;
    int tid = threadIdx.x;
    int r = tid >> 3;          // 0..31
    int c4 = (tid & 7) * 4;    // 0..28
    float4 v = *(const float4*)&W[(size_t)(k0 + r) * 1024 + n0 + c4];
    t[r][c4 + 0] = v.x; t[r][c4 + 1] = v.y; t[r][c4 + 2] = v.z; t[r][c4 + 3] = v.w;
    __syncthreads();
    half_t* o = Wt + (size_t)blockIdx.z * 1024 * 1024 + (size_t)(n0 + r) * 1024 + k0 + c4;
    h16x4 h;
    h[0] = (half_t)t[c4 + 0][r];
    h[1] = (half_t)t[c4 + 1][r];
    h[2] = (half_t)t[c4 + 2][r];
    h[3] = (half_t)t[c4 + 3][r];
    *(h16x4*)o = h;
}

// ---------------------------------------------------------------------------
// Kernel 1: QKV projection GEMM.  Y = xh @ W + b.
// Q,K stored [bh][s][hd] fp16;  V stored TRANSPOSED [bh][hd][s] fp16.
// grid (8, 32, 3), block 256 (4 waves 2x2), tile 128x128, BK=32.
// ---------------------------------------------------------------------------
__global__ __launch_bounds__(256) void gemm_qkv_kernel(
    const half_t* __restrict__ xh,   // [4096][1024]
    const half_t* __restrict__ Wt,   // [3][1024 n][1024 k]
    const float* __restrict__ bq, const float* __restrict__ bk,
    const float* __restrict__ bv,
    half_t* __restrict__ qkv)
{
    const int p = blockIdx.z;
    const float* bias = (p == 0) ? bq : ((p == 1) ? bk : bv);
    const half_t* Wp = Wt + (size_t)p * 1024 * 1024;
    const int n0 = blockIdx.x * 128, m0 = blockIdx.y * 128;

    __shared__ half_t Al[128][40];
    __shared__ half_t Bl[128][40];

    const int tid = threadIdx.x;
    const int lane = tid & 63, wid = tid >> 6;
    const int wm = wid >> 1, wn = wid & 1;
    const int g = lane >> 4, r = lane & 15;

    const int sr = tid >> 2;
    const int sc = (tid & 3) * 8;

    f32x4 acc[4][4];
#pragma unroll
    for (int a = 0; a < 4; a++)
#pragma unroll
        for (int c = 0; c < 4; c++) acc[a][c] = (f32x4){0.f, 0.f, 0.f, 0.f};

    for (int k0 = 0; k0 < 1024; k0 += 32) {
        __syncthreads();
        *(h16x8*)&Al[sr][sc]      = *(const h16x8*)&xh[(size_t)(m0 + sr) * 1024 + k0 + sc];
        *(h16x8*)&Al[sr + 64][sc] = *(const h16x8*)&xh[(size_t)(m0 + sr + 64) * 1024 + k0 + sc];
        *(h16x8*)&Bl[sr][sc]      = *(const h16x8*)&Wp[(size_t)(n0 + sr) * 1024 + k0 + sc];
        *(h16x8*)&Bl[sr + 64][sc] = *(const h16x8*)&Wp[(size_t)(n0 + sr + 64) * 1024 + k0 + sc];
        __syncthreads();

        h16x8 af[4], bf[4];
#pragma unroll
        for (int mi = 0; mi < 4; mi++)
            af[mi] = *(const h16x8*)&Al[wm * 64 + mi * 16 + r][g * 8];
#pragma unroll
        for (int ni = 0; ni < 4; ni++)
            bf[ni] = *(const h16x8*)&Bl[wn * 64 + ni * 16 + r][g * 8];
#pragma unroll
        for (int mi = 0; mi < 4; mi++)
#pragma unroll
            for (int ni = 0; ni < 4; ni++)
                acc[mi][ni] = MFMA16(af[mi], bf[ni], acc[mi][ni]);
    }

    float bn[4];
#pragma unroll
    for (int ni = 0; ni < 4; ni++) bn[ni] = bias[n0 + wn * 64 + ni * 16 + r];

    if (p == 2) {
        // V: store transposed [bh][hd][s], packed 4 consecutive s per store
        half_t* outp = qkv + (size_t)2 * 4194304;
#pragma unroll
        for (int mi = 0; mi < 4; mi++) {
            int m = m0 + wm * 64 + mi * 16 + g * 4;
            int b = m >> 11, s = m & 2047;
#pragma unroll
            for (int ni = 0; ni < 4; ni++) {
                int n = n0 + wn * 64 + ni * 16 + r;
                int h = n >> 6, hd = n & 63;
                h16x4 pk;
#pragma unroll
                for (int i = 0; i < 4; i++) pk[i] = (half_t)(acc[mi][ni][i] + bn[ni]);
                *(h16x4*)&outp[((size_t)(b * 16 + h) * 64 + hd) * 2048 + s] = pk;
            }
        }
    } else {
        half_t* outp = qkv + (size_t)p * 4194304;
#pragma unroll
        for (int mi = 0; mi < 4; mi++) {
#pragma unroll
            for (int ni = 0; ni < 4; ni++) {
                int n = n0 + wn * 64 + ni * 16 + r;
                int h = n >> 6, hd = n & 63;
#pragma unroll
                for (int i = 0; i < 4; i++) {
                    int m = m0 + wm * 64 + mi * 16 + g * 4 + i;
                    int b = m >> 11, s = m & 2047;
                    float v = acc[mi][ni][i] + bn[ni];
                    outp[(((size_t)(b * 16 + h) * 2048 + s) << 6) + hd] = (half_t)v;
                }
            }
        }
    }
}

// ---------------------------------------------------------------------------
// Kernel 2: flash attention.  grid (S/128=16, B*H=32), block 512 (8 waves).
// Wave owns 16 q-rows. KVBLK=64. Swapped QK^T (in-lane softmax),
// double-buffered K/V LDS with async-stage split. No softmax scaling.
// ---------------------------------------------------------------------------
__global__ __launch_bounds__(512, 4) void attn_kernel(
    const half_t* __restrict__ Qg,  // [32][2048][64]
    const half_t* __restrict__ Kg,  // [32][2048][64]
    const half_t* __restrict__ Vtg, // [32][64][2048]  (V transposed)
    float* __restrict__ out)        // [B][S][1024]
{
    __shared__ half_t Kl[2][64][72];
    __shared__ half_t Vl[2][64][72];
    __shared__ half_t Pl[8][16][72];

    const int tid = threadIdx.x;
    const int lane = tid & 63, wid = tid >> 6;
    const int g = lane >> 4, r = lane & 15;
    const int bh = blockIdx.y;
    const int b = bh >> 4, h = bh & 15;
    const half_t* Qb = Qg + (size_t)bh * 131072;
    const half_t* Kb = Kg + (size_t)bh * 131072;
    const half_t* Vb = Vtg + (size_t)bh * 131072;
    const int q0 = blockIdx.x * 128 + wid * 16;

    // hoisted Q fragments (rows q0+r, two 32-k halves)
    h16x8 qf[2];
    qf[0] = *(const h16x8*)&Qb[(size_t)(q0 + r) * 64 + g * 8];
    qf[1] = *(const h16x8*)&Qb[(size_t)(q0 + r) * 64 + 32 + g * 8];

    f32x4 o[4];
#pragma unroll
    for (int d = 0; d < 4; d++) o[d] = (f32x4){0.f, 0.f, 0.f, 0.f};
    float m_run = -1e30f, l_run = 0.f;   // per-lane state for q = lane&15

    const int srow = tid >> 3;          // 0..63
    const int sc8 = (tid & 7) * 8;      // 0..56

    // prologue: stage tile 0
    {
        h16x8 k0 = *(const h16x8*)&Kb[srow * 64 + sc8];
        h16x8 v0 = *(const h16x8*)&Vb[(size_t)srow * 2048 + sc8];
        *(h16x8*)&Kl[0][srow][sc8] = k0;
        *(h16x8*)&Vl[0][srow][sc8] = v0;
    }

    h16x8 kreg, vreg;
    int cur = 0;

    auto compute_tile = [&](int cb) {
        // QK^T (swapped): lane holds E[k = kc*16 + g*4 + i][q = lane&15]
        f32x4 e[4];
#pragma unroll
        for (int kc = 0; kc < 4; kc++) {
            e[kc] = (f32x4){0.f, 0.f, 0.f, 0.f};
#pragma unroll
            for (int t = 0; t < 2; t++) {
                h16x8 kf = *(const h16x8*)&Kl[cb][kc * 16 + r][t * 32 + g * 8];
                e[kc] = MFMA16(kf, qf[t], e[kc]);
            }
        }

        // in-lane online softmax for q = lane&15 (replicated across 4 g-groups)
        float tm = e[0][0];
#pragma unroll
        for (int kc = 0; kc < 4; kc++)
#pragma unroll
            for (int i = 0; i < 4; i++) tm = fmaxf(tm, e[kc][i]);
        tm = fmaxf(tm, __shfl_xor(tm, 16));
        tm = fmaxf(tm, __shfl_xor(tm, 32));
        float nm = fmaxf(m_run, tm);
        float sc = __expf(m_run - nm);
        m_run = nm;
        float ps = 0.f;
#pragma unroll
        for (int kc = 0; kc < 4; kc++)
#pragma unroll
            for (int i = 0; i < 4; i++) {
                float pv = __expf(e[kc][i] - nm);
                e[kc][i] = pv;
                ps += pv;
            }
        ps += __shfl_xor(ps, 16);
        ps += __shfl_xor(ps, 32);
        l_run = l_run * sc + ps;

        // rescale O: o[d][i] belongs to q = g*4+i; fetch that q's scale
#pragma unroll
        for (int i = 0; i < 4; i++) {
            float sci = __shfl(sc, (lane & 48) | (g * 4 + i));
#pragma unroll
            for (int d = 0; d < 4; d++) o[d][i] *= sci;
        }

        // P -> per-wave LDS (packed 4-half writes), then PV
#pragma unroll
        for (int kc = 0; kc < 4; kc++) {
            h16x4 pk;
#pragma unroll
            for (int i = 0; i < 4; i++) pk[i] = (half_t)e[kc][i];
            *(h16x4*)&Pl[wid][r][kc * 16 + g * 4] = pk;
        }
        asm volatile("s_waitcnt lgkmcnt(0)" ::: "memory");
        __builtin_amdgcn_sched_barrier(0);

#pragma unroll
        for (int ks = 0; ks < 2; ks++) {
            h16x8 pf = *(const h16x8*)&Pl[wid][r][ks * 32 + g * 8];
#pragma unroll
            for (int d = 0; d < 4; d++) {
                h16x8 vf = *(const h16x8*)&Vl[cb][d * 16 + r][ks * 32 + g * 8];
                o[d] = MFMA16(pf, vf, o[d]);
            }
        }
    };

    for (int kt = 0; kt < 31; ++kt) {
        // issue next-tile global loads (latency hides under compute)
        kreg = *(const h16x8*)&Kb[(kt + 1) * 4096 + srow * 64 + sc8];
        vreg = *(const h16x8*)&Vb[(size_t)srow * 2048 + (kt + 1) * 64 + sc8];
        __syncthreads();
        compute_tile(cur);
        // write next tile into the other buffer (vmcnt wait inserted here)
        *(h16x8*)&Kl[cur ^ 1][srow][sc8] = kreg;
        *(h16x8*)&Vl[cur ^ 1][srow][sc8] = vreg;
        cur ^= 1;
    }
    __syncthreads();
    compute_tile(cur);

    // epilogue
#pragma unroll
    for (int i = 0; i < 4; i++) {
        float li = __shfl(l_run, (lane & 48) | (g * 4 + i));
        float inv = 1.0f / li;
        int s = q0 + g * 4 + i;
        float* op = out + (size_t)(b * 2048 + s) * 1024 + h * 64 + r;
#pragma unroll
        for (int d = 0; d < 4; d++) op[d * 16] = o[d][i] * inv;
    }
}

// ---------------------------------------------------------------------------
extern "C" void kernel_launch(void* const* d_in, const int* in_sizes, int n_in,
                              void* d_out, int out_size, void* d_ws, size_t ws_size,
                              hipStream_t stream) {
    const float* x  = (const float*)d_in[0];
    const float* Wq = (const float*)d_in[1];
    const float* bq = (const float*)d_in[2];
    const float* Wk = (const float*)d_in[3];
    const float* bk = (const float*)d_in[4];
    const float* Wv = (const float*)d_in[5];
    const float* bv = (const float*)d_in[6];
    float* out = (float*)d_out;

    half_t* xh  = (half_t*)d_ws;
    half_t* Wt  = (half_t*)((char*)d_ws + (size_t)8 * 1024 * 1024);
    half_t* qkv = (half_t*)((char*)d_ws + (size_t)14 * 1024 * 1024);
    half_t* Qh  = qkv;
    half_t* Kh  = qkv + (size_t)4194304;
    half_t* Vth = qkv + (size_t)8388608;

    cvt_x_kernel<<<2048, 256, 0, stream>>>(x, xh, 524288);
    cvt_w_kernel<<<dim3(32, 32, 3), 256, 0, stream>>>(Wq, Wk, Wv, Wt);
    gemm_qkv_kernel<<<dim3(8, 32, 3), 256, 0, stream>>>(xh, Wt, bq, bk, bv, qkv);
    attn_kernel<<<dim3(16, 32), 512, 0, stream>>>(Qh, Kh, Vth, out);
}